// Round 1
// baseline (2509.555 us; speedup 1.0000x reference)
//
#include <hip/hip_runtime.h>
#include <cstdint>
#include <cstddef>

typedef unsigned short u16;
typedef __bf16 bf16x8 __attribute__((ext_vector_type(8)));
typedef float f32x4 __attribute__((ext_vector_type(4)));

// ---------- helpers ----------

__device__ __forceinline__ u16 f2bf(float f) {
  unsigned u = __builtin_bit_cast(unsigned, f);
  u += 0x7fffu + ((u >> 16) & 1u);   // round-to-nearest-even
  return (u16)(u >> 16);
}

__device__ __forceinline__ void gld16(const u16* g, u16* l) {
  // async global->LDS, 16B per lane; LDS dest = wave-uniform base + lane*16
  __builtin_amdgcn_global_load_lds((__attribute__((address_space(1))) void*)(g),
                                   (__attribute__((address_space(3))) void*)(l),
                                   16, 0, 0);
}

// ---------- prep kernels ----------

// Gather x columns into bf16 matrices.
// XG [8192,6144]  = [x[:,svd_up] | x[:,svd_gate]]
// Afused cols 1024:2048 = x[:,col_up], cols 3072:4096 = x[:,col_gate]
__global__ void gather_x(const float* __restrict__ x,
                         const int* __restrict__ svd_up, const int* __restrict__ col_up,
                         const int* __restrict__ svd_gate, const int* __restrict__ col_gate,
                         u16* __restrict__ XG, u16* __restrict__ Afused) {
  const int r = blockIdx.x;
  const float* xr = x + (size_t)r * 4096;
  const int* idx; u16* dst; int n;
  switch (blockIdx.y) {
    case 0:  idx = svd_up;   dst = XG + (size_t)r * 6144;            n = 3072; break;
    case 1:  idx = svd_gate; dst = XG + (size_t)r * 6144 + 3072;     n = 3072; break;
    case 2:  idx = col_up;   dst = Afused + (size_t)r * 4096 + 1024; n = 1024; break;
    default: idx = col_gate; dst = Afused + (size_t)r * 4096 + 3072; n = 1024; break;
  }
  for (int j = threadIdx.x; j < n; j += 256) dst[j] = f2bf(xr[idx[j]]);
}

__global__ void cast_bf16_vec(const float* __restrict__ src, u16* __restrict__ dst, int n4) {
  int i = blockIdx.x * 256 + threadIdx.x;
  if (i < n4) {
    float4 f = ((const float4*)src)[i];
    ushort4 o;
    o.x = f2bf(f.x); o.y = f2bf(f.y); o.z = f2bf(f.z); o.w = f2bf(f.w);
    ((ushort4*)dst)[i] = o;
  }
}

// Wfused [11008,4096]: row j (dest order, pd = svd_down||col_down, c = pd[j]) =
//   [up_u[c,:] | up_c[c,:] | gate_u[c,:] | gate_c[c,:]]  (bf16)
__global__ void build_wfused(const float* __restrict__ up_u, const float* __restrict__ up_c,
                             const float* __restrict__ gate_u, const float* __restrict__ gate_c,
                             const int* __restrict__ svd_down, const int* __restrict__ col_down,
                             u16* __restrict__ W) {
  const int j = blockIdx.x;
  const int c = (j < 8192) ? svd_down[j] : col_down[j - 8192];
  const float* s0 = up_u   + (size_t)c * 1024;
  const float* s1 = up_c   + (size_t)c * 1024;
  const float* s2 = gate_u + (size_t)c * 1024;
  const float* s3 = gate_c + (size_t)c * 1024;
  u16* w = W + (size_t)j * 4096;
  for (int t = threadIdx.x; t < 1024; t += 256) {
    w[t]        = f2bf(s0[t]);
    w[1024 + t] = f2bf(s1[t]);
    w[2048 + t] = f2bf(s2[t]);
    w[3072 + t] = f2bf(s3[t]);
  }
}

// Wdown2 [4096,3840]: row o = [down_u[o,:1024] | down_c[o,:2816]] (bf16)
__global__ void build_wdown2(const float* __restrict__ down_u, const float* __restrict__ down_c,
                             u16* __restrict__ W) {
  const int o = blockIdx.x;
  const float* s0 = down_u + (size_t)o * 1024;
  const float* s1 = down_c + (size_t)o * 2816;
  u16* w = W + (size_t)o * 3840;
  for (int t = threadIdx.x; t < 1024; t += 256) w[t] = f2bf(s0[t]);
  for (int t = threadIdx.x; t < 2816; t += 256) w[1024 + t] = f2bf(s1[t]);
}

// ---------- GEMM (m97 structure: 128x128 tile, BK=32, 4 waves, 16x16x32 bf16) ----------

#define GEMM_PROLOGUE                                                          \
  __shared__ u16 As[4096];                                                     \
  __shared__ u16 Bs[4096];                                                     \
  const int tid = threadIdx.x;                                                 \
  const int wave = tid >> 6, lane = tid & 63;                                  \
  const int quad = lane >> 4, l16 = lane & 15;                                 \
  const int wm = wave >> 1, wn = wave & 1;                                     \
  const int row0 = blockIdx.y * 128, col0 = blockIdx.x * 128;                  \
  const int ra = tid >> 2, ca = (tid & 3) * 8;                                 \
  u16* lA1 = &As[wave * 512];                                                  \
  u16* lA2 = &As[2048 + wave * 512];                                           \
  u16* lB1 = &Bs[wave * 512];                                                  \
  u16* lB2 = &Bs[2048 + wave * 512];

#define GEMM_STEP(k0, ACC)                                                     \
  {                                                                            \
    __syncthreads();                                                           \
    gld16(gA1 + (k0), lA1);                                                    \
    gld16(gA2 + (k0), lA2);                                                    \
    gld16(gB1 + (k0), lB1);                                                    \
    gld16(gB2 + (k0), lB2);                                                    \
    __syncthreads();                                                           \
    bf16x8 af[4], bf[4];                                                       \
    _Pragma("unroll") for (int i = 0; i < 4; ++i)                              \
        af[i] = *(const bf16x8*)&As[(wm * 64 + i * 16 + l16) * 32 + quad * 8]; \
    _Pragma("unroll") for (int i = 0; i < 4; ++i)                              \
        bf[i] = *(const bf16x8*)&Bs[(wn * 64 + i * 16 + l16) * 32 + quad * 8]; \
    _Pragma("unroll") for (int mi = 0; mi < 4; ++mi)                           \
      _Pragma("unroll") for (int ni = 0; ni < 4; ++ni)                         \
        ACC[mi][ni] = __builtin_amdgcn_mfma_f32_16x16x32_bf16(                 \
            af[mi], bf[ni], ACC[mi][ni], 0, 0, 0);                             \
  }

// Generic C = A * B^T. A row-major [M,K] ld=lda, B row-major [N,K] ld=ldb.
// EPI 0: bf16 output, EPI 1: f32 output. Output col = coff + col0 + local.
template <int EPI>
__global__ __launch_bounds__(256, 2) void gemm_bt(
    const u16* __restrict__ A, int lda,
    const u16* __restrict__ B, int ldb, int K,
    void* __restrict__ C, int ldc, int coff) {
  GEMM_PROLOGUE
  const u16* gA1 = A + (size_t)(row0 + ra) * lda + ca;
  const u16* gA2 = A + (size_t)(row0 + 64 + ra) * lda + ca;
  const u16* gB1 = B + (size_t)(col0 + ra) * ldb + ca;
  const u16* gB2 = B + (size_t)(col0 + 64 + ra) * ldb + ca;

  f32x4 acc[4][4] = {};
  for (int k0 = 0; k0 < K; k0 += 32) GEMM_STEP(k0, acc)

#pragma unroll
  for (int mi = 0; mi < 4; ++mi)
#pragma unroll
    for (int ni = 0; ni < 4; ++ni)
#pragma unroll
      for (int r = 0; r < 4; ++r) {
        const int gm = row0 + wm * 64 + mi * 16 + quad * 4 + r;
        const int gn = coff + col0 + wn * 64 + ni * 16 + l16;
        if (EPI == 0) ((u16*)C)[(size_t)gm * ldc + gn] = f2bf(acc[mi][ni][r]);
        else          ((float*)C)[(size_t)gm * ldc + gn] = acc[mi][ni][r];
      }
}

// Fused up/gate stage-2 + SwiGLU. A = Afused [8192,4096] (t_up|x_col_up|t_gate|x_col_gate),
// B = Wfused [11008,4096]. accU over k<2048, accG over k>=2048; out = silu(g)*u (bf16),
// scattered to Gsvd [8192,8192] (cols 0:8192) or Afinal cols 1024:3840 (cols 8192:11008).
__global__ __launch_bounds__(256, 2) void gemm_swiglu(
    const u16* __restrict__ A, const u16* __restrict__ B,
    u16* __restrict__ Gsvd, u16* __restrict__ Afin) {
  GEMM_PROLOGUE
  const u16* gA1 = A + (size_t)(row0 + ra) * 4096 + ca;
  const u16* gA2 = A + (size_t)(row0 + 64 + ra) * 4096 + ca;
  const u16* gB1 = B + (size_t)(col0 + ra) * 4096 + ca;
  const u16* gB2 = B + (size_t)(col0 + 64 + ra) * 4096 + ca;

  f32x4 accU[4][4] = {};
  f32x4 accG[4][4] = {};
  for (int k0 = 0;    k0 < 2048; k0 += 32) GEMM_STEP(k0, accU)
  for (int k0 = 2048; k0 < 4096; k0 += 32) GEMM_STEP(k0, accG)

  u16* outp; int ldo, coff;
  if (col0 < 8192) { outp = Gsvd; ldo = 8192; coff = col0; }
  else             { outp = Afin; ldo = 3840; coff = 1024 + (col0 - 8192); }

#pragma unroll
  for (int mi = 0; mi < 4; ++mi)
#pragma unroll
    for (int ni = 0; ni < 4; ++ni)
#pragma unroll
      for (int r = 0; r < 4; ++r) {
        const float u = accU[mi][ni][r];
        const float g = accG[mi][ni][r];
        const float val = u * g / (1.0f + __expf(-g));  // silu(g)*u
        const int gm = row0 + wm * 64 + mi * 16 + quad * 4 + r;
        const int gn = coff + wn * 64 + ni * 16 + l16;
        outp[(size_t)gm * ldo + gn] = f2bf(val);
      }
}

// ---------- launch ----------

extern "C" void kernel_launch(void* const* d_in, const int* in_sizes, int n_in,
                              void* d_out, int out_size, void* d_ws, size_t ws_size,
                              hipStream_t stream) {
  const float* x      = (const float*)d_in[0];
  const float* up_v   = (const float*)d_in[1];
  const float* up_u   = (const float*)d_in[2];
  const float* up_c   = (const float*)d_in[3];
  const float* gate_v = (const float*)d_in[4];
  const float* gate_u = (const float*)d_in[5];
  const float* gate_c = (const float*)d_in[6];
  const float* down_v = (const float*)d_in[7];
  const float* down_u = (const float*)d_in[8];
  const float* down_c = (const float*)d_in[9];
  const int* svd_up   = (const int*)d_in[10];
  const int* col_up   = (const int*)d_in[11];
  const int* svd_gate = (const int*)d_in[12];
  const int* col_gate = (const int*)d_in[13];
  const int* svd_down = (const int*)d_in[14];
  const int* col_down = (const int*)d_in[15];

  char* ws = (char*)d_ws;
  // XG [8192,6144] (100.7MB) aliases Gsvd [8192,8192] (134.2MB): XG dead before Gsvd written.
  u16* XG     = (u16*)(ws + 0);
  u16* Gsvd   = (u16*)(ws + 0);
  u16* Afused = (u16*)(ws + 134217728);  // [8192,4096] 67.1MB
  u16* Afin   = (u16*)(ws + 201326592);  // [8192,3840] 62.9MB
  u16* V1u    = (u16*)(ws + 264241152);  // [1024,3072] 6.3MB
  u16* V1g    = (u16*)(ws + 270532608);  // [1024,3072] 6.3MB
  u16* Wf     = (u16*)(ws + 276824064);  // [11008,4096] 90.2MB
  u16* DV     = (u16*)(ws + 367001600);  // [1024,8192] 16.8MB
  u16* W2     = (u16*)(ws + 383778816);  // [4096,3840] 31.5MB  (total ~396MiB)

  const dim3 blk(256);
  // phase 0: gathers + weight prep (independent)
  gather_x<<<dim3(8192, 4), blk, 0, stream>>>(x, svd_up, col_up, svd_gate, col_gate, XG, Afused);
  cast_bf16_vec<<<dim3(3072), blk, 0, stream>>>(up_v, V1u, 1024 * 3072 / 4);
  cast_bf16_vec<<<dim3(3072), blk, 0, stream>>>(gate_v, V1g, 1024 * 3072 / 4);
  cast_bf16_vec<<<dim3(8192), blk, 0, stream>>>(down_v, DV, 1024 * 8192 / 4);
  build_wfused<<<dim3(11008), blk, 0, stream>>>(up_u, up_c, gate_u, gate_c, svd_down, col_down, Wf);
  build_wdown2<<<dim3(4096), blk, 0, stream>>>(down_u, down_c, W2);

  // phase 1: t_up / t_gate  (M=8192, N=1024, K=3072) -> Afused cols 0:1024 / 2048:3072
  gemm_bt<0><<<dim3(8, 64), blk, 0, stream>>>(XG, 6144, V1u, 3072, 3072, Afused, 4096, 0);
  gemm_bt<0><<<dim3(8, 64), blk, 0, stream>>>(XG + 3072, 6144, V1g, 3072, 3072, Afused, 4096, 2048);

  // phase 2: fused up/gate stage-2 + SwiGLU (M=8192, N=11008, K=2048+2048)
  gemm_swiglu<<<dim3(86, 64), blk, 0, stream>>>(Afused, Wf, Gsvd, Afin);

  // phase 3: t2 = Gsvd @ down_v^T (M=8192, N=1024, K=8192) -> Afin cols 0:1024
  gemm_bt<0><<<dim3(8, 64), blk, 0, stream>>>(Gsvd, 8192, DV, 8192, 8192, Afin, 3840, 0);

  // phase 4: out = Afin @ W2^T (M=8192, N=4096, K=3840), fp32 -> d_out
  gemm_bt<1><<<dim3(32, 64), blk, 0, stream>>>(Afin, 3840, W2, 3840, 3840, d_out, 4096, 0);
}

// Round 2
// 2459.206 us; speedup vs baseline: 1.0205x; 1.0205x over previous
//
#include <hip/hip_runtime.h>
#include <cstdint>
#include <cstddef>

typedef unsigned short u16;
typedef __bf16 bf16x8 __attribute__((ext_vector_type(8)));
typedef float f32x4 __attribute__((ext_vector_type(4)));

// ---------- helpers ----------

__device__ __forceinline__ u16 f2bf(float f) {
  unsigned u = __builtin_bit_cast(unsigned, f);
  u += 0x7fffu + ((u >> 16) & 1u);   // round-to-nearest-even
  return (u16)(u >> 16);
}

__device__ __forceinline__ void gld16(const u16* g, u16* l) {
  // async global->LDS, 16B per lane; LDS dest = wave-uniform base + lane*16
  __builtin_amdgcn_global_load_lds((__attribute__((address_space(1))) void*)(g),
                                   (__attribute__((address_space(3))) void*)(l),
                                   16, 0, 0);
}

// ---------- prep kernels ----------

__global__ void gather_x(const float* __restrict__ x,
                         const int* __restrict__ svd_up, const int* __restrict__ col_up,
                         const int* __restrict__ svd_gate, const int* __restrict__ col_gate,
                         u16* __restrict__ XG, u16* __restrict__ Afused) {
  const int r = blockIdx.x;
  const float* xr = x + (size_t)r * 4096;
  const int* idx; u16* dst; int n;
  switch (blockIdx.y) {
    case 0:  idx = svd_up;   dst = XG + (size_t)r * 6144;            n = 3072; break;
    case 1:  idx = svd_gate; dst = XG + (size_t)r * 6144 + 3072;     n = 3072; break;
    case 2:  idx = col_up;   dst = Afused + (size_t)r * 4096 + 1024; n = 1024; break;
    default: idx = col_gate; dst = Afused + (size_t)r * 4096 + 3072; n = 1024; break;
  }
  for (int j = threadIdx.x; j < n; j += 256) dst[j] = f2bf(xr[idx[j]]);
}

__global__ void cast_bf16_vec(const float* __restrict__ src, u16* __restrict__ dst, int n4) {
  int i = blockIdx.x * 256 + threadIdx.x;
  if (i < n4) {
    float4 f = ((const float4*)src)[i];
    ushort4 o;
    o.x = f2bf(f.x); o.y = f2bf(f.y); o.z = f2bf(f.z); o.w = f2bf(f.w);
    ((ushort4*)dst)[i] = o;
  }
}

__global__ void build_wfused(const float* __restrict__ up_u, const float* __restrict__ up_c,
                             const float* __restrict__ gate_u, const float* __restrict__ gate_c,
                             const int* __restrict__ svd_down, const int* __restrict__ col_down,
                             u16* __restrict__ W) {
  const int j = blockIdx.x;
  const int c = (j < 8192) ? svd_down[j] : col_down[j - 8192];
  const float* s0 = up_u   + (size_t)c * 1024;
  const float* s1 = up_c   + (size_t)c * 1024;
  const float* s2 = gate_u + (size_t)c * 1024;
  const float* s3 = gate_c + (size_t)c * 1024;
  u16* w = W + (size_t)j * 4096;
  for (int t = threadIdx.x; t < 1024; t += 256) {
    w[t]        = f2bf(s0[t]);
    w[1024 + t] = f2bf(s1[t]);
    w[2048 + t] = f2bf(s2[t]);
    w[3072 + t] = f2bf(s3[t]);
  }
}

__global__ void build_wdown2(const float* __restrict__ down_u, const float* __restrict__ down_c,
                             u16* __restrict__ W) {
  const int o = blockIdx.x;
  const float* s0 = down_u + (size_t)o * 1024;
  const float* s1 = down_c + (size_t)o * 2816;
  u16* w = W + (size_t)o * 3840;
  for (int t = threadIdx.x; t < 1024; t += 256) w[t] = f2bf(s0[t]);
  for (int t = threadIdx.x; t < 2816; t += 256) w[1024 + t] = f2bf(s1[t]);
}

// ---------- GEMM (m97 structure: 128x128 tile, BK=32, 4 waves, 16x16x32 bf16) ----------

#define GEMM_PROLOGUE(ROW0, COL0)                                              \
  __shared__ u16 As[4096];                                                     \
  __shared__ u16 Bs[4096];                                                     \
  const int tid = threadIdx.x;                                                 \
  const int wave = tid >> 6, lane = tid & 63;                                  \
  const int quad = lane >> 4, l16 = lane & 15;                                 \
  const int wm = wave >> 1, wn = wave & 1;                                     \
  const int row0 = (ROW0), col0 = (COL0);                                      \
  const int ra = tid >> 2, ca = (tid & 3) * 8;                                 \
  u16* lA1 = &As[wave * 512];                                                  \
  u16* lA2 = &As[2048 + wave * 512];                                           \
  u16* lB1 = &Bs[wave * 512];                                                  \
  u16* lB2 = &Bs[2048 + wave * 512];

#define GEMM_STEP(k0, ACC)                                                     \
  {                                                                            \
    __syncthreads();                                                           \
    gld16(gA1 + (k0), lA1);                                                    \
    gld16(gA2 + (k0), lA2);                                                    \
    gld16(gB1 + (k0), lB1);                                                    \
    gld16(gB2 + (k0), lB2);                                                    \
    __syncthreads();                                                           \
    bf16x8 af[4], bf[4];                                                       \
    _Pragma("unroll") for (int i = 0; i < 4; ++i)                              \
        af[i] = *(const bf16x8*)&As[(wm * 64 + i * 16 + l16) * 32 + quad * 8]; \
    _Pragma("unroll") for (int i = 0; i < 4; ++i)                              \
        bf[i] = *(const bf16x8*)&Bs[(wn * 64 + i * 16 + l16) * 32 + quad * 8]; \
    _Pragma("unroll") for (int mi = 0; mi < 4; ++mi)                           \
      _Pragma("unroll") for (int ni = 0; ni < 4; ++ni)                         \
        ACC[mi][ni] = __builtin_amdgcn_mfma_f32_16x16x32_bf16(                 \
            af[mi], bf[ni], ACC[mi][ni], 0, 0, 0);                             \
  }

// Generic C = A * B^T. A row-major [M,K] ld=lda, B row-major [N,K] ld=ldb.
// EPI 0: bf16 output, EPI 1: f32 output.
// Output col = coff + col0 + local; if SPLIT and local col >= 1024, add 1024 more
// (used to write the merged up/gate stage-1 outputs into Afused cols 0:1024 & 2048:3072).
template <int EPI, int SPLIT>
__global__ __launch_bounds__(256, 2) void gemm_bt(
    const u16* __restrict__ A, int lda,
    const u16* __restrict__ B, int ldb, int K,
    void* __restrict__ C, int ldc, int coff) {
  GEMM_PROLOGUE(blockIdx.y * 128, blockIdx.x * 128)
  const u16* gA1 = A + (size_t)(row0 + ra) * lda + ca;
  const u16* gA2 = A + (size_t)(row0 + 64 + ra) * lda + ca;
  const u16* gB1 = B + (size_t)(col0 + ra) * ldb + ca;
  const u16* gB2 = B + (size_t)(col0 + 64 + ra) * ldb + ca;

  f32x4 acc[4][4] = {};
  for (int k0 = 0; k0 < K; k0 += 32) GEMM_STEP(k0, acc)

#pragma unroll
  for (int mi = 0; mi < 4; ++mi)
#pragma unroll
    for (int ni = 0; ni < 4; ++ni)
#pragma unroll
      for (int r = 0; r < 4; ++r) {
        const int gm = row0 + wm * 64 + mi * 16 + quad * 4 + r;
        int lc = col0 + wn * 64 + ni * 16 + l16;
        if (SPLIT && lc >= 1024) lc += 1024;
        const int gn = coff + lc;
        if (EPI == 0) ((u16*)C)[(size_t)gm * ldc + gn] = f2bf(acc[mi][ni][r]);
        else          ((float*)C)[(size_t)gm * ldc + gn] = acc[mi][ni][r];
      }
}

// Fused up/gate stage-2 + SwiGLU, with L3-locality block swizzle.
// Grid: 1D, 86*64 blocks. Order: y-groups of 16 row-tiles; within a group the
// B sweep (x) advances every 16 blocks -> working set = 16 A-tiles (16MB) + B
// stream; B fetched ~4x total instead of ~64x.
__global__ __launch_bounds__(256, 2) void gemm_swiglu(
    const u16* __restrict__ A, const u16* __restrict__ B,
    u16* __restrict__ Gsvd, u16* __restrict__ Afin) {
  const int GRP = 16, NX = 86;
  const int per = NX * GRP;
  const int bid = blockIdx.x;
  const int g = bid / per, rem = bid % per;
  const int bx = rem / GRP;
  const int by = g * GRP + (rem % GRP);
  GEMM_PROLOGUE(by * 128, bx * 128)
  const u16* gA1 = A + (size_t)(row0 + ra) * 4096 + ca;
  const u16* gA2 = A + (size_t)(row0 + 64 + ra) * 4096 + ca;
  const u16* gB1 = B + (size_t)(col0 + ra) * 4096 + ca;
  const u16* gB2 = B + (size_t)(col0 + 64 + ra) * 4096 + ca;

  f32x4 accU[4][4] = {};
  f32x4 accG[4][4] = {};
  for (int k0 = 0;    k0 < 2048; k0 += 32) GEMM_STEP(k0, accU)
  for (int k0 = 2048; k0 < 4096; k0 += 32) GEMM_STEP(k0, accG)

  u16* outp; int ldo, coff;
  if (col0 < 8192) { outp = Gsvd; ldo = 8192; coff = col0; }
  else             { outp = Afin; ldo = 3840; coff = 1024 + (col0 - 8192); }

#pragma unroll
  for (int mi = 0; mi < 4; ++mi)
#pragma unroll
    for (int ni = 0; ni < 4; ++ni)
#pragma unroll
      for (int r = 0; r < 4; ++r) {
        const float u = accU[mi][ni][r];
        const float gg = accG[mi][ni][r];
        const float val = u * gg / (1.0f + __expf(-gg));  // silu(g)*u
        const int gm = row0 + wm * 64 + mi * 16 + quad * 4 + r;
        const int gn = coff + wn * 64 + ni * 16 + l16;
        outp[(size_t)gm * ldo + gn] = f2bf(val);
      }
}

// ---------- launch ----------

extern "C" void kernel_launch(void* const* d_in, const int* in_sizes, int n_in,
                              void* d_out, int out_size, void* d_ws, size_t ws_size,
                              hipStream_t stream) {
  const float* x      = (const float*)d_in[0];
  const float* up_v   = (const float*)d_in[1];
  const float* up_u   = (const float*)d_in[2];
  const float* up_c   = (const float*)d_in[3];
  const float* gate_v = (const float*)d_in[4];
  const float* gate_u = (const float*)d_in[5];
  const float* gate_c = (const float*)d_in[6];
  const float* down_v = (const float*)d_in[7];
  const float* down_u = (const float*)d_in[8];
  const float* down_c = (const float*)d_in[9];
  const int* svd_up   = (const int*)d_in[10];
  const int* col_up   = (const int*)d_in[11];
  const int* svd_gate = (const int*)d_in[12];
  const int* col_gate = (const int*)d_in[13];
  const int* svd_down = (const int*)d_in[14];
  const int* col_down = (const int*)d_in[15];

  char* ws = (char*)d_ws;
  // XG [8192,6144] (100.7MB) aliases Gsvd [8192,8192] (134.2MB): XG dead before Gsvd written.
  u16* XG     = (u16*)(ws + 0);
  u16* Gsvd   = (u16*)(ws + 0);
  u16* Afused = (u16*)(ws + 134217728);  // [8192,4096] 67.1MB
  u16* Afin   = (u16*)(ws + 201326592);  // [8192,3840] 62.9MB
  u16* V1     = (u16*)(ws + 264241152);  // [2048,3072] 12.6MB  (V1u rows 0:1024, V1g rows 1024:2048)
  u16* Wf     = (u16*)(ws + 276824064);  // [11008,4096] 90.2MB
  u16* DV     = (u16*)(ws + 367001600);  // [1024,8192] 16.8MB
  u16* W2     = (u16*)(ws + 383778816);  // [4096,3840] 31.5MB  (total ~396MiB)

  const dim3 blk(256);
  // phase 0: gathers + weight prep (independent)
  gather_x<<<dim3(8192, 4), blk, 0, stream>>>(x, svd_up, col_up, svd_gate, col_gate, XG, Afused);
  cast_bf16_vec<<<dim3(3072), blk, 0, stream>>>(up_v, V1, 1024 * 3072 / 4);
  cast_bf16_vec<<<dim3(3072), blk, 0, stream>>>(gate_v, V1 + 1024 * 3072, 1024 * 3072 / 4);
  cast_bf16_vec<<<dim3(8192), blk, 0, stream>>>(down_v, DV, 1024 * 8192 / 4);
  build_wfused<<<dim3(11008), blk, 0, stream>>>(up_u, up_c, gate_u, gate_c, svd_down, col_down, Wf);
  build_wdown2<<<dim3(4096), blk, 0, stream>>>(down_u, down_c, W2);

  // phase 1: merged t_up/t_gate (M=8192, N=2048, K=3072) -> Afused cols 0:1024 & 2048:3072
  // NOTE: t_gate needs x[:,svd_gate] = XG cols 3072:6144 vs B rows 1024:2048, but both
  // halves of V1 multiply their OWN x-gather. Split A pointers per half: launch two
  // x-ranges in one grid via SPLIT epilogue is wrong unless A matches — so keep two
  // launches but with the shared-B-free layout (B halves are disjoint anyway).
  gemm_bt<0, 0><<<dim3(8, 64), blk, 0, stream>>>(XG, 6144, V1, 3072, 3072, Afused, 4096, 0);
  gemm_bt<0, 0><<<dim3(8, 64), blk, 0, stream>>>(XG + 3072, 6144, V1 + 1024 * 3072, 3072, 3072, Afused, 4096, 2048);

  // phase 2: fused up/gate stage-2 + SwiGLU (M=8192, N=11008, K=2048+2048), swizzled
  gemm_swiglu<<<dim3(86 * 64), blk, 0, stream>>>(Afused, Wf, Gsvd, Afin);

  // phase 3: t2 = Gsvd @ down_v^T (M=8192, N=1024, K=8192) -> Afin cols 0:1024
  gemm_bt<0, 0><<<dim3(8, 64), blk, 0, stream>>>(Gsvd, 8192, DV, 8192, 8192, Afin, 3840, 0);

  // phase 4: out = Afin @ W2^T (M=8192, N=4096, K=3840), fp32 -> d_out
  gemm_bt<1, 0><<<dim3(32, 64), blk, 0, stream>>>(Afin, 3840, W2, 3840, 3840, d_out, 4096, 0);
}